// Round 13
// baseline (72.289 us; speedup 1.0000x reference)
//
#include <hip/hip_runtime.h>
#include <math.h>

#define NROWS 8192
#define DIM 512
#define INV_T 20.0f
#define QS 500.0f
// dequant * 1/T * log2(e), for exp2-based softmax accumulation
#define DEQ2 (INV_T * 1.4426950408889634f / (QS * QS))

typedef __attribute__((ext_vector_type(4))) int i32x4;

__device__ __forceinline__ void gload_lds16(const void* g, void* l) {
    __builtin_amdgcn_global_load_lds(
        (const __attribute__((address_space(1))) unsigned int*)g,
        (__attribute__((address_space(3))) unsigned int*)l, 16, 0, 0);
}

__device__ __forceinline__ float hw_exp2(float x) {
    float r;
    asm("v_exp_f32 %0, %1" : "=v"(r) : "v"(x));  // D = 2^S0, 1 inst
    return r;
}

__device__ __forceinline__ float dot4(float4 a, float4 b) {
    return a.x * b.x + a.y * b.y + a.z * b.z + a.w * b.w;
}

__device__ __forceinline__ int q4(float4 v, float s) {
    int b0 = __float2int_rn(fminf(fmaxf(v.x * s, -127.f), 127.f)) & 255;
    int b1 = __float2int_rn(fminf(fmaxf(v.y * s, -127.f), 127.f)) & 255;
    int b2 = __float2int_rn(fminf(fmaxf(v.z * s, -127.f), 127.f)) & 255;
    int b3 = __float2int_rn(fminf(fmaxf(v.w * s, -127.f), 127.f)) & 255;
    return b0 | (b1 << 8) | (b2 << 16) | (b3 << 24);
}

// One wave per row: L2-normalize, quantize to i8 (scale QS), exact fp32 diag,
// column log2-weights (0 or 1), zero row-sum accumulator.
__global__ __launch_bounds__(256) void norm_kernel(
    const float* __restrict__ A, const float* __restrict__ S,
    const int* __restrict__ labels, signed char* __restrict__ aQ,
    signed char* __restrict__ sQ, float* __restrict__ diag,
    float* __restrict__ lw2, float* __restrict__ lsum) {
    const int wave = threadIdx.x >> 6, lane = threadIdx.x & 63;
    const int row = blockIdx.x * 4 + wave;
    const float4* a4 = (const float4*)(A + (size_t)row * DIM);
    const float4* s4 = (const float4*)(S + (size_t)row * DIM);
    float4 a0 = a4[lane], a1 = a4[lane + 64];
    float4 s0 = s4[lane], s1 = s4[lane + 64];
    float saa = dot4(a0, a0) + dot4(a1, a1);
    float sss = dot4(s0, s0) + dot4(s1, s1);
    float sas = dot4(a0, s0) + dot4(a1, s1);
    for (int m = 1; m < 64; m <<= 1) {
        saa += __shfl_xor(saa, m);
        sss += __shfl_xor(sss, m);
        sas += __shfl_xor(sas, m);
    }
    const float ra = rsqrtf(saa), rs = rsqrtf(sss);
    signed char* arow = aQ + (size_t)row * DIM;
    signed char* srow = sQ + (size_t)row * DIM;
    *(int*)(arow + lane * 4)       = q4(a0, ra * QS);
    *(int*)(arow + 256 + lane * 4) = q4(a1, ra * QS);
    *(int*)(srow + lane * 4)       = q4(s0, rs * QS);
    *(int*)(srow + 256 + lane * 4) = q4(s1, rs * QS);
    if (lane == 0) {
        diag[row] = sas * ra * rs * INV_T;
        // Uniform column weighting (incl. diagonal) is exact for the final
        // loss: only label==1 rows' lse is consumed, and those rows' diagonal
        // column has log_w==0 in the reference anyway. log2-weight: 0 or 1.
        lw2[row] = (labels[row] == 0) ? 1.0f : 0.0f;
        lsum[row] = 0.0f;
    }
}

// ---------------------------------------------------------------------------
// A-in-registers fused i8 GEMM + exp2 + row-sum (v13).
// Rationale (r4-r12 bound analysis): with 64x64 wave tiles, LDS operand
// delivery is 4 MB/CU ~ 49k cyc > MFMA floor 42k cyc -> every prior
// structure was LDS-bound. Fix: hold the wave's FULL A operand set (64 rows
// x K=512 = 128 VGPR) in registers for the whole kernel; LDS serves only B
// (2 MB/CU reads ~ 20k cyc << 42k) -> MFMA-bound at last.
// Block = 8 waves x 64 rows = 512 rows, sweeping 8 ct x 64 cols = one CU's
// 512x512 output region. Grid 256 = 1 block/CU. Per ct: stage next B tile
// (64 cols x 512 B = 32 KB, dbuf), 128 MFMA/wave from regs+LDS, in-cage
// epilogue, vmcnt(0)+barrier -> ONE barrier per ~2600 MFMA-cycles.
// B swizzle: 32-slot XOR slot^(col&7), involution on global source (rule
// 21), uniform bank-quad spread. A prologue: 8 pipelined 32 KB LDS chunks
// (r12-verified 4-slot swizzle), lgkmcnt(0) before re-staging a just-read
// buffer (gload-after-ds_read same-buffer hazard).
// ---------------------------------------------------------------------------
__global__ __launch_bounds__(512, 2) void lse_gemm(
    const signed char* __restrict__ Aq, const signed char* __restrict__ Bq,
    const float* __restrict__ lw2, float* __restrict__ lsum) {
    __shared__ __align__(16) char lds[65536];  // 2 x 32 KB buffers

    const int bid = blockIdx.x;  // 256 blocks = 1 per CU
    const int xcd = bid & 7, idx = bid >> 3;    // bid%8 -> XCD
    const int rt = (xcd >> 1) * 4 + (idx & 3);  // 0..15 (512-row tile)
    const int cg = (xcd & 1) * 8 + (idx >> 2);  // 0..15 (512-col group)
    const int row0 = rt * 512;
    const int colg = cg * 512;

    const int tid = threadIdx.x;
    const int wid = tid >> 6, lane = tid & 63;
    const int fr = lane & 15, grp = lane >> 4;

    // ---- A chunk staging (prologue): chunk k = A[row0..+512, k*64..+64),
    // 32 KB. Thread t, load i: row = i*128 + (t>>2), phys slot t&3; fetch
    // logical slot (t&3)^((t>>3)&3) [r3/r4/r12-verified 4-slot involution].
    const int slA = (tid & 3) ^ ((tid >> 3) & 3);
    const signed char* aSrc = Aq + (size_t)(row0 + (tid >> 2)) * DIM + slA * 16;
#define STAGE_A(B, K)                                                         \
    do {                                                                      \
        _Pragma("unroll")                                                     \
        for (int i = 0; i < 4; ++i)                                           \
            gload_lds16(aSrc + (size_t)i * 65536 + (K) * 64,                  \
                        lds + (B) * 32768 + i * 8192 + tid * 16);             \
    } while (0)

    // ---- B tile staging: tile ct = B[colg+ct*64 ..+64, full K] = 32 KB,
    // col-major (col c at c*512). Thread t, load i: col = i*16 + (t>>5),
    // phys slot t&31; fetch logical slot (t&31)^(col&7) = (t&31)^((t>>5)&7)
    // [32-slot involution; i*16 = 0 mod 8 -> i-independent].
    const int slB = (tid & 31) ^ ((tid >> 5) & 7);
    const signed char* bSrc = Bq + (size_t)(colg + (tid >> 5)) * DIM + slB * 16;
#define STAGE_B(B, CT)                                                        \
    do {                                                                      \
        _Pragma("unroll")                                                     \
        for (int i = 0; i < 4; ++i)                                           \
            gload_lds16(bSrc + (size_t)(CT) * 32768 + i * 8192,               \
                        lds + (B) * 32768 + i * 8192 + tid * 16);             \
    } while (0)

    // A fragment reads (prologue): row wid*64 + m*16 + fr, phys slot
    // grp ^ ((fr>>1)&3)  [r12-identical].
    const int psA = (grp ^ ((fr >> 1) & 3)) << 4;
    const char* rdA = lds + (wid * 64 + fr) * 64 + psA;

    i32x4 a[4][8];  // the wave's full A operand set: 128 VGPRs

    // ---- pipelined A prologue: chunks 0..7 through the 2 buffers
    STAGE_A(0, 0);
    STAGE_A(1, 1);
#pragma unroll
    for (int k = 0; k < 8; ++k) {
        if (k < 7)
            asm volatile("s_waitcnt vmcnt(4)" ::: "memory");  // chunk k done
        else
            asm volatile("s_waitcnt vmcnt(4)" ::: "memory");  // B0 pending
        __builtin_amdgcn_s_barrier();  // all waves' chunk-k loads landed
#pragma unroll
        for (int m = 0; m < 4; ++m)
            a[m][k] = *(const i32x4*)(rdA + (k & 1) * 32768 + m * 1024);
        // gload-after-ds_read same-buffer hazard: drain our reads first
        asm volatile("s_waitcnt lgkmcnt(0)" ::: "memory");
        __builtin_amdgcn_s_barrier();  // all waves read chunk k
        if (k < 6) STAGE_A(k & 1, k + 2);
        if (k == 6) STAGE_B(0, 0);  // buf0 free; B(ct=0) in flight
    }
    asm volatile("s_waitcnt vmcnt(0)" ::: "memory");  // B0 staged
    __builtin_amdgcn_s_barrier();

    // ---- main ct sweep: 8 x {stage next B, 128 MFMA, epilogue, barrier}
#pragma unroll 1
    for (int ct = 0; ct < 8; ++ct) {
        if (ct < 7) STAGE_B((ct + 1) & 1, ct + 1);

        const char* rdB = lds + (ct & 1) * 32768;
        i32x4 acc[4][4] = {};
#pragma unroll
        for (int k = 0; k < 8; ++k) {
            i32x4 b[4];
#pragma unroll
            for (int n = 0; n < 4; ++n)
                b[n] = *(const i32x4*)(rdB + (n * 16 + fr) * 512 +
                                       (((k * 4 + grp) ^ (fr & 7)) << 4));
#pragma unroll
            for (int m = 0; m < 4; ++m)
#pragma unroll
                for (int n = 0; n < 4; ++n)
                    acc[m][n] = __builtin_amdgcn_mfma_i32_16x16x64_i8(
                        a[m][k], b[n], acc[m][n], 0, 0, 0);
        }

        // in-cage register-lean epilogue (r10/r12-proven form)
        const int col0 = colg + ct * 64;
        float lwv[4];
#pragma unroll
        for (int n = 0; n < 4; ++n)
            lwv[n] = lw2[col0 + n * 16 + fr];
#pragma unroll
        for (int m = 0; m < 4; ++m)
#pragma unroll
            for (int j = 0; j < 4; ++j) {
                float s = 0.f;
#pragma unroll
                for (int n = 0; n < 4; ++n)
                    s += hw_exp2(fmaf((float)acc[m][n][j], DEQ2, lwv[n]));
                s += __shfl_xor(s, 1);
                s += __shfl_xor(s, 2);
                s += __shfl_xor(s, 4);
                s += __shfl_xor(s, 8);
                if (fr == 0)
                    atomicAdd(&lsum[row0 + wid * 64 + m * 16 + grp * 4 + j], s);
            }

        asm volatile("s_waitcnt vmcnt(0)" ::: "memory");  // B(ct+1) staged
        __builtin_amdgcn_s_barrier();  // all waves done reading B(ct)
    }
#undef STAGE_A
#undef STAGE_B
}

// 1024 threads, single block: final scalar reduction.
__global__ __launch_bounds__(1024) void finalize_kernel(
    const float* __restrict__ lsum, const float* __restrict__ diag,
    const int* __restrict__ labels, float* __restrict__ out) {
    const int tid = threadIdx.x;
    float sl = 0.f, sd = 0.f, mx = -1e9f;
    int np_ = 0, nn_ = 0;
#pragma unroll
    for (int i = tid; i < NROWS; i += 1024) {
        const float dg = diag[i];
        if (labels[i] == 1) {
            sl += logf(lsum[i]) - dg;
            sd += dg;
            np_++;
        } else {
            nn_++;
            mx = fmaxf(mx, dg);
        }
    }
    for (int m = 1; m < 64; m <<= 1) {
        sl += __shfl_xor(sl, m);
        sd += __shfl_xor(sd, m);
        mx = fmaxf(mx, __shfl_xor(mx, m));
        np_ += __shfl_xor(np_, m);
        nn_ += __shfl_xor(nn_, m);
    }
    __shared__ float rsl[16], rsd[16], rmx[16];
    __shared__ int rnp[16], rnn[16];
    const int wave = tid >> 6, lane = tid & 63;
    if (lane == 0) {
        rsl[wave] = sl; rsd[wave] = sd; rmx[wave] = mx;
        rnp[wave] = np_; rnn[wave] = nn_;
    }
    __syncthreads();
    if (tid == 0) {
        float SL = 0.f, SD = 0.f, MX = -1e9f;
        int NP = 0, NN = 0;
        for (int w = 0; w < 16; w++) {
            SL += rsl[w]; SD += rsd[w]; MX = fmaxf(MX, rmx[w]);
            NP += rnp[w]; NN += rnn[w];
        }
        const float infonce = SL / (float)NP;
        const float meanpos = SD / (float)NP;
        float pen = fmaxf(MX - meanpos + 0.2f, 0.0f);
        if (NN == 0) pen = 0.0f;
        out[0] = infonce + pen;
    }
}

extern "C" void kernel_launch(void* const* d_in, const int* in_sizes, int n_in,
                              void* d_out, int out_size, void* d_ws, size_t ws_size,
                              hipStream_t stream) {
    const float* A = (const float*)d_in[0];
    const float* S = (const float*)d_in[1];
    const int* labels = (const int*)d_in[2];
    float* out = (float*)d_out;

    char* ws = (char*)d_ws;
    signed char* aQ = (signed char*)ws;                          // 4 MB
    signed char* sQ = (signed char*)(ws + (size_t)NROWS * DIM);  // 4 MB
    char* p = ws + (size_t)NROWS * DIM * 2;
    float* diag = (float*)p;                // 32 KB
    float* lw2 = (float*)(p + 32768);       // 32 KB
    float* lsum = (float*)(p + 65536);      // 32 KB

    norm_kernel<<<NROWS / 4, 256, 0, stream>>>(A, S, labels, aQ, sQ, diag, lw2, lsum);
    lse_gemm<<<256, 512, 0, stream>>>(aQ, sQ, lw2, lsum);
    finalize_kernel<<<1, 1024, 0, stream>>>(lsum, diag, labels, out);
}

// Round 14
// 66.661 us; speedup vs baseline: 1.0844x; 1.0844x over previous
//
#include <hip/hip_runtime.h>
#include <math.h>

#define NROWS 8192
#define DIM 512
#define INV_T 20.0f
#define QS 500.0f
// dequant * 1/T * log2(e), for exp2-based softmax accumulation
#define DEQ2 (INV_T * 1.4426950408889634f / (QS * QS))

typedef __attribute__((ext_vector_type(4))) int i32x4;

__device__ __forceinline__ void gload_lds16(const void* g, void* l) {
    __builtin_amdgcn_global_load_lds(
        (const __attribute__((address_space(1))) unsigned int*)g,
        (__attribute__((address_space(3))) unsigned int*)l, 16, 0, 0);
}

__device__ __forceinline__ void block_bar() {
    asm volatile("" ::: "memory");
    __builtin_amdgcn_s_barrier();
    asm volatile("" ::: "memory");
}

__device__ __forceinline__ float hw_exp2(float x) {
    float r;
    asm("v_exp_f32 %0, %1" : "=v"(r) : "v"(x));  // D = 2^S0, 1 inst
    return r;
}

__device__ __forceinline__ float dot4(float4 a, float4 b) {
    return a.x * b.x + a.y * b.y + a.z * b.z + a.w * b.w;
}

__device__ __forceinline__ int q4(float4 v, float s) {
    int b0 = __float2int_rn(fminf(fmaxf(v.x * s, -127.f), 127.f)) & 255;
    int b1 = __float2int_rn(fminf(fmaxf(v.y * s, -127.f), 127.f)) & 255;
    int b2 = __float2int_rn(fminf(fmaxf(v.z * s, -127.f), 127.f)) & 255;
    int b3 = __float2int_rn(fminf(fmaxf(v.w * s, -127.f), 127.f)) & 255;
    return b0 | (b1 << 8) | (b2 << 16) | (b3 << 24);
}

// One wave per row: L2-normalize, quantize to i8 (scale QS), exact fp32 diag,
// column log2-weights (0 or 1), zero row-sum accumulator.
__global__ __launch_bounds__(256) void norm_kernel(
    const float* __restrict__ A, const float* __restrict__ S,
    const int* __restrict__ labels, signed char* __restrict__ aQ,
    signed char* __restrict__ sQ, float* __restrict__ diag,
    float* __restrict__ lw2, float* __restrict__ lsum) {
    const int wave = threadIdx.x >> 6, lane = threadIdx.x & 63;
    const int row = blockIdx.x * 4 + wave;
    const float4* a4 = (const float4*)(A + (size_t)row * DIM);
    const float4* s4 = (const float4*)(S + (size_t)row * DIM);
    float4 a0 = a4[lane], a1 = a4[lane + 64];
    float4 s0 = s4[lane], s1 = s4[lane + 64];
    float saa = dot4(a0, a0) + dot4(a1, a1);
    float sss = dot4(s0, s0) + dot4(s1, s1);
    float sas = dot4(a0, s0) + dot4(a1, s1);
    for (int m = 1; m < 64; m <<= 1) {
        saa += __shfl_xor(saa, m);
        sss += __shfl_xor(sss, m);
        sas += __shfl_xor(sas, m);
    }
    const float ra = rsqrtf(saa), rs = rsqrtf(sss);
    signed char* arow = aQ + (size_t)row * DIM;
    signed char* srow = sQ + (size_t)row * DIM;
    *(int*)(arow + lane * 4)       = q4(a0, ra * QS);
    *(int*)(arow + 256 + lane * 4) = q4(a1, ra * QS);
    *(int*)(srow + lane * 4)       = q4(s0, rs * QS);
    *(int*)(srow + 256 + lane * 4) = q4(s1, rs * QS);
    if (lane == 0) {
        diag[row] = sas * ra * rs * INV_T;
        // Uniform column weighting (incl. diagonal) is exact for the final
        // loss: only label==1 rows' lse is consumed, and those rows' diagonal
        // column has log_w==0 in the reference anyway. log2-weight: 0 or 1.
        lw2[row] = (labels[row] == 0) ? 1.0f : 0.0f;
        lsum[row] = 0.0f;
    }
}

// ---------------------------------------------------------------------------
// Phased i8 GEMM + exp2 + row-sum (v14 = r12 engine with PHASE-SHIFTED
// operand reads, per the m201/m233 skeleton).
// r12's 2-phase loop = the documented ~27%-MfmaUtil structure: ds_reads
// issued after the stage-barrier, drained immediately before MFMA (fully
// exposed latency). v14 issues step T+1's ds_reads at the END of step T
// (after B2), draining them at T+1's lgkmcnt(0) -> read latency hides under
// B2 + other waves' MFMA + staging issue. Counted vmcnt(3) keeps a full
// MFMA phase of lead time and never blocks issue.
// Geometry (r12-identical): 512 thr = 8 waves (4x2), tile 256x128 sweeping
// 4 cts -> 32 K-steps; 48 KB LDS dbuf -> 2 blocks/CU; swizzles r3/r4-
// verified; epilogue register-lean in-cage (covered by the other block).
// ---------------------------------------------------------------------------
__global__ __launch_bounds__(512, 4) void lse_gemm(
    const signed char* __restrict__ Aq, const signed char* __restrict__ Bq,
    const float* __restrict__ lw2, float* __restrict__ lsum) {
    __shared__ __align__(16) char lds[49152];
    // buf layout (stride 24576): A 16 KB @0, B 8 KB @16384

    const int bid = blockIdx.x;  // 512 blocks = 2 per CU
    const int xcd = bid & 7, idx = bid >> 3;     // bid%8 -> XCD
    const int rt = (xcd >> 1) * 8 + (idx & 7);   // 0..31 (256-row tile)
    const int ctg = (xcd & 1) * 8 + (idx >> 3);  // 0..15 (512-col group)
    const int row0 = rt * 256;
    const int colg = ctg * 512;

    const int tid = threadIdx.x;
    const int wid = tid >> 6, lane = tid & 63;
    const int wr = wid >> 1, wc = wid & 1;  // 4x2 wave grid (64x64 each)
    const int fr = lane & 15, grp = lane >> 4;

    // staging: thread t -> row t>>2 (A also +128 via second load), phys slot
    // t&3; fetch logical slot (t&3)^((t>>3)&3)  [4-slot involution, verified]
    const int sl = (tid & 3) ^ ((tid >> 3) & 3);
    const signed char* aSrc = Aq + (size_t)(row0 + (tid >> 2)) * DIM + sl * 16;
    const signed char* bSrc = Bq + (size_t)(colg + (tid >> 2)) * DIM + sl * 16;
    char* dstA = lds + tid * 16;          // + buf*24576 (+8192 for rows 128+)
    char* dstB = lds + 16384 + tid * 16;  // + buf*24576

    // K-step TT (0..31): ct = TT>>3, k = TT&7. 3 loads per thread per step.
#define STAGE(buf, TT)                                                        \
    do {                                                                      \
        const int ct_ = (TT) >> 3, k_ = (TT) & 7;                             \
        gload_lds16(aSrc + k_ * 64,               dstA + (buf) * 24576);      \
        gload_lds16(aSrc + 65536 + k_ * 64,       dstA + (buf) * 24576 + 8192); \
        gload_lds16(bSrc + ct_ * 65536 + k_ * 64, dstB + (buf) * 24576);      \
    } while (0)

    // fragment reads: A row R = wr*64 + m*16 + fr at byte R*64 + ps;
    // B row = wc*64 + n*16 + fr. ps = (grp ^ ((fr>>1)&3))*16.
    const int ps = (grp ^ ((fr >> 1) & 3)) << 4;
    const char* rdA = lds + (wr * 64 + fr) * 64 + ps;
    const char* rdB = lds + 16384 + (wc * 64 + fr) * 64 + ps;

    // ---- prologue: stage T0, sync, pre-read T0, launch T1 staging
    STAGE(0, 0);
    asm volatile("s_waitcnt vmcnt(0)" ::: "memory");
    block_bar();

    i32x4 a[4], b[4];
#pragma unroll
    for (int m = 0; m < 4; ++m)
        a[m] = *(const i32x4*)(rdA + m * 1024);
#pragma unroll
    for (int n = 0; n < 4; ++n)
        b[n] = *(const i32x4*)(rdB + n * 1024);
    STAGE(1, 1);

    i32x4 acc[4][4] = {};
#pragma unroll 2
    for (int T = 0; T < 32; ++T) {
        const int buf = T & 1;

        // operands for T were pre-issued; drain and compute
        asm volatile("s_waitcnt lgkmcnt(0)" ::: "memory");
        __builtin_amdgcn_sched_barrier(0);  // rule 18: pin MFMA after lgkm
        __builtin_amdgcn_s_setprio(1);
#pragma unroll
        for (int m = 0; m < 4; ++m)
#pragma unroll
            for (int n = 0; n < 4; ++n)
                acc[m][n] = __builtin_amdgcn_mfma_i32_16x16x64_i8(
                    a[m], b[n], acc[m][n], 0, 0, 0);
        __builtin_amdgcn_s_setprio(0);

        if ((T & 7) == 7) {
            // register-lean in-cage epilogue (r10/r12-proven): dequant ->
            // exp2 -> 16-lane reduce -> atomicAdd; other block covers it.
            const int ct = T >> 3;
            const int col0 = colg + ct * 128 + wc * 64;
            float lwv[4];
#pragma unroll
            for (int n = 0; n < 4; ++n)
                lwv[n] = lw2[col0 + n * 16 + fr];
#pragma unroll
            for (int m = 0; m < 4; ++m)
#pragma unroll
                for (int j = 0; j < 4; ++j) {
                    float s = 0.f;
#pragma unroll
                    for (int n = 0; n < 4; ++n)
                        s += hw_exp2(fmaf((float)acc[m][n][j], DEQ2, lwv[n]));
                    s += __shfl_xor(s, 1);
                    s += __shfl_xor(s, 2);
                    s += __shfl_xor(s, 4);
                    s += __shfl_xor(s, 8);
                    if (fr == 0)
                        atomicAdd(&lsum[row0 + wr * 64 + m * 16 + grp * 4 + j], s);
                }
#pragma unroll
            for (int m = 0; m < 4; ++m)
#pragma unroll
                for (int n = 0; n < 4; ++n)
                    acc[m][n] = i32x4{0, 0, 0, 0};
        }

        block_bar();  // B1: all waves' lgkm(0) passed -> buf[T&1] reads done

        if (T <= 29) {
            STAGE(buf, T + 2);  // refill the just-freed buffer
            // FIFO vmcnt: waits until <=3 outstanding -> T+1's 3 loads landed
            asm volatile("s_waitcnt vmcnt(3)" ::: "memory");
        } else if (T == 30) {
            asm volatile("s_waitcnt vmcnt(0)" ::: "memory");  // drain T=31
        }

        if (T < 31) {
            block_bar();  // B2: every wave confirmed T+1 staged
            // pre-issue reads for T+1; drained at next lgkmcnt(0)
#pragma unroll
            for (int m = 0; m < 4; ++m)
                a[m] = *(const i32x4*)(rdA + (buf ^ 1) * 24576 + m * 1024);
#pragma unroll
            for (int n = 0; n < 4; ++n)
                b[n] = *(const i32x4*)(rdB + (buf ^ 1) * 24576 + n * 1024);
        }
    }
#undef STAGE
}

// 1024 threads, single block: final scalar reduction.
__global__ __launch_bounds__(1024) void finalize_kernel(
    const float* __restrict__ lsum, const float* __restrict__ diag,
    const int* __restrict__ labels, float* __restrict__ out) {
    const int tid = threadIdx.x;
    float sl = 0.f, sd = 0.f, mx = -1e9f;
    int np_ = 0, nn_ = 0;
#pragma unroll
    for (int i = tid; i < NROWS; i += 1024) {
        const float dg = diag[i];
        if (labels[i] == 1) {
            sl += logf(lsum[i]) - dg;
            sd += dg;
            np_++;
        } else {
            nn_++;
            mx = fmaxf(mx, dg);
        }
    }
    for (int m = 1; m < 64; m <<= 1) {
        sl += __shfl_xor(sl, m);
        sd += __shfl_xor(sd, m);
        mx = fmaxf(mx, __shfl_xor(mx, m));
        np_ += __shfl_xor(np_, m);
        nn_ += __shfl_xor(nn_, m);
    }
    __shared__ float rsl[16], rsd[16], rmx[16];
    __shared__ int rnp[16], rnn[16];
    const int wave = tid >> 6, lane = tid & 63;
    if (lane == 0) {
        rsl[wave] = sl; rsd[wave] = sd; rmx[wave] = mx;
        rnp[wave] = np_; rnn[wave] = nn_;
    }
    __syncthreads();
    if (tid == 0) {
        float SL = 0.f, SD = 0.f, MX = -1e9f;
        int NP = 0, NN = 0;
        for (int w = 0; w < 16; w++) {
            SL += rsl[w]; SD += rsd[w]; MX = fmaxf(MX, rmx[w]);
            NP += rnp[w]; NN += rnn[w];
        }
        const float infonce = SL / (float)NP;
        const float meanpos = SD / (float)NP;
        float pen = fmaxf(MX - meanpos + 0.2f, 0.0f);
        if (NN == 0) pen = 0.0f;
        out[0] = infonce + pen;
    }
}

extern "C" void kernel_launch(void* const* d_in, const int* in_sizes, int n_in,
                              void* d_out, int out_size, void* d_ws, size_t ws_size,
                              hipStream_t stream) {
    const float* A = (const float*)d_in[0];
    const float* S = (const float*)d_in[1];
    const int* labels = (const int*)d_in[2];
    float* out = (float*)d_out;

    char* ws = (char*)d_ws;
    signed char* aQ = (signed char*)ws;                          // 4 MB
    signed char* sQ = (signed char*)(ws + (size_t)NROWS * DIM);  // 4 MB
    char* p = ws + (size_t)NROWS * DIM * 2;
    float* diag = (float*)p;                // 32 KB
    float* lw2 = (float*)(p + 32768);       // 32 KB
    float* lsum = (float*)(p + 65536);      // 32 KB

    norm_kernel<<<NROWS / 4, 256, 0, stream>>>(A, S, labels, aQ, sQ, diag, lw2, lsum);
    lse_gemm<<<512, 512, 0, stream>>>(aQ, sQ, lw2, lsum);
    finalize_kernel<<<1, 1024, 0, stream>>>(lsum, diag, labels, out);
}